// Round 2
// baseline (762.066 us; speedup 1.0000x reference)
//
#include <hip/hip_runtime.h>
#include <hip/hip_bf16.h>
#include <cstdint>

// Problem constants: B_=2048 windows, N=64 tokens, C=512, H=16 heads, hd=32, nW=64.
typedef __bf16 bf16;
typedef __bf16 bf16x8_t __attribute__((ext_vector_type(8)));
typedef __bf16 bf16x4_t __attribute__((ext_vector_type(4)));
typedef float  f32x4_t  __attribute__((ext_vector_type(4)));

#define MFMA16(a, b, c) __builtin_amdgcn_mfma_f32_16x16x32_bf16((a), (b), (c), 0, 0, 0)

__device__ __forceinline__ void gload_lds16(const bf16* g, bf16* l) {
    __builtin_amdgcn_global_load_lds(
        (const __attribute__((address_space(1))) void*)g,
        (__attribute__((address_space(3))) void*)l,
        16, 0, 0);
}

// ---------------------------------------------------------------------------
// Kernel 1: convert weights to bf16 (qkv_w 1536x512, proj_w 512x512)
// ---------------------------------------------------------------------------
__global__ void k_wprep(const float* __restrict__ wq, const float* __restrict__ wp,
                        bf16* __restrict__ wqb, bf16* __restrict__ wpb) {
    int t = blockIdx.x * 256 + threadIdx.x;
    int stride = gridDim.x * 256;
    for (int i = t; i < 196608; i += stride) {
        float4 v = ((const float4*)wq)[i];
        bf16x4_t o; o[0]=(bf16)v.x; o[1]=(bf16)v.y; o[2]=(bf16)v.z; o[3]=(bf16)v.w;
        ((bf16x4_t*)wqb)[i] = o;
    }
    for (int i = t; i < 65536; i += stride) {
        float4 v = ((const float4*)wp)[i];
        bf16x4_t o; o[0]=(bf16)v.x; o[1]=(bf16)v.y; o[2]=(bf16)v.z; o[3]=(bf16)v.w;
        ((bf16x4_t*)wpb)[i] = o;
    }
}

// ---------------------------------------------------------------------------
// Kernel 2: fused QKV-projection + window attention.
// 1024 blocks x 512 threads (8 waves). Each block: 2 windows.
// Wave w: window win=w>>2 of the pair, token strip rows [16*(w&3), +16).
// W tile (96 rows for head h x BK=128) staged via global_load_lds with
// both-sides XOR swizzle (rule #21): source piece pre-swizzled, ds_read
// applies the same involution -> linear LDS, balanced banks.
// ---------------------------------------------------------------------------
__global__ __launch_bounds__(512, 4) void k_qkv_attn(
    const float* __restrict__ x,     // (2048,64,512) f32
    const float* __restrict__ pe,    // (64,512) f32
    const float* __restrict__ rpe,   // (16,64,64) f32
    const float* __restrict__ mask,  // (64,64,64) f32
    const float* __restrict__ qkv_b, // (1536,) f32
    const bf16*  __restrict__ wq,    // (1536,512) bf16
    bf16* __restrict__ ao)           // (2048,64,512) bf16 out
{
    __shared__ bf16 Ws[96 * 128];     // [96][128] unpadded, XOR-swizzled. 24576 B
    __shared__ bf16 qs[2][64 * 40];   // q   [64][32] pad 40, per window
    __shared__ bf16 ks[2][64 * 40];   // k
    __shared__ bf16 vts[2][32 * 72];  // v^T [32][64] pad 72
    __shared__ bf16 ps[2][64 * 72];   // P   [64][64] pad 72
    // total LDS = 72,704 B -> 2 blocks/CU

    const int tid  = threadIdx.x;
    const int lane = tid & 63;
    const int wave = tid >> 6;
    const int win  = wave >> 2;       // 0/1: which window of the pair
    const int lr   = lane & 15;
    const int lg   = lane >> 4;
    const int row0 = (wave & 3) * 16;
    const int b2   = blockIdx.x * 2 + win;
    const int wi   = b2 & 63;         // mask window index

    // ---- xp strip into registers: a[kc] covers k = kc*32 + lg*8 .. +8
    bf16x8_t a[16];
    {
        const float* xr = x  + ((size_t)(b2 * 64 + row0 + lr)) * 512;
        const float* pr = pe + (size_t)(row0 + lr) * 512;
#pragma unroll
        for (int kc = 0; kc < 16; ++kc) {
            int k = kc * 32 + lg * 8;
            float4 x0 = *(const float4*)(xr + k);
            float4 x1 = *(const float4*)(xr + k + 4);
            float4 p0 = *(const float4*)(pr + k);
            float4 p1 = *(const float4*)(pr + k + 4);
            bf16x8_t v;
            v[0]=(bf16)(x0.x+p0.x); v[1]=(bf16)(x0.y+p0.y);
            v[2]=(bf16)(x0.z+p0.z); v[3]=(bf16)(x0.w+p0.w);
            v[4]=(bf16)(x1.x+p1.x); v[5]=(bf16)(x1.y+p1.y);
            v[6]=(bf16)(x1.z+p1.z); v[7]=(bf16)(x1.w+p1.w);
            a[kc] = v;
        }
    }

    const float SCALE = 0.17677669529663687f;  // 32^-0.5

    for (int h = 0; h < 16; ++h) {
        // ---------------- QKV head-GEMM: out 64x96 (q|k|v) per window, K=512
        f32x4_t acc[6] = {};
#pragma unroll
        for (int kt = 0; kt < 4; ++kt) {          // BK=128
            // stage Ws: 24 KB = 24 x 1KB instrs, 3 per wave, swizzled source
#pragma unroll
            for (int ii = 0; ii < 3; ++ii) {
                int instr = wave * 3 + ii;        // 0..23
                int r  = instr * 4 + (lane >> 4); // LDS row 0..95
                int s  = lane & 15;               // physical 16B slot
                int gp = (s & 8) | ((s & 7) ^ (r & 7));      // logical piece
                int R  = ((r >> 5) << 9) + (h << 5) + (r & 31); // W global row
                gload_lds16(wq + (size_t)R * 512 + kt * 128 + gp * 8,
                            &Ws[instr * 512]);
            }
            __syncthreads();   // drains vmcnt -> Ws ready; also closes prev reads
#pragma unroll
            for (int k2 = 0; k2 < 4; ++k2) {
                const int kc = kt * 4 + k2;       // compile-time
#pragma unroll
                for (int j = 0; j < 6; ++j) {
                    int row  = j * 16 + lr;
                    int p    = k2 * 4 + lg;
                    int phys = (p & 8) | ((p & 7) ^ (row & 7));
                    bf16x8_t bfrag = *(const bf16x8_t*)&Ws[row * 128 + phys * 8];
                    acc[j] = MFMA16(a[kc], bfrag, acc[j]);
                }
            }
            __syncthreads();   // reads done before next kt's staging overwrites
        }

        // ---------------- bias + scatter q/k/v to LDS ------------------------
#pragma unroll
        for (int j = 0; j < 6; ++j) {
            int which = j >> 1;
            int colh  = (j & 1) * 16 + lr;
            float bj = qkv_b[which * 512 + h * 32 + colh];
#pragma unroll
            for (int r = 0; r < 4; ++r) {
                int row = row0 + lg * 4 + r;
                float val = acc[j][r] + bj;
                if (which == 0)      qs[win][row * 40 + colh] = (bf16)val;
                else if (which == 1) ks[win][row * 40 + colh] = (bf16)val;
                else                 vts[win][colh * 72 + row] = (bf16)val;
            }
        }
        __syncthreads();

        // ---------------- prefetch rpe+mask (hides L2 latency under S-MFMA) --
        const float* rp = rpe  + ((size_t)h)  * 4096;
        const float* mp = mask + ((size_t)wi) * 4096;
        float rm[4][4];
#pragma unroll
        for (int j = 0; j < 4; ++j) {
            int col = j * 16 + lr;
#pragma unroll
            for (int r = 0; r < 4; ++r) {
                int row = row0 + lg * 4 + r;
                rm[j][r] = rp[row * 64 + col] + mp[row * 64 + col];
            }
        }

        // ---------------- S = q k^T (strip 16 x 64), K=32 --------------------
        bf16x8_t aq = *(const bf16x8_t*)&qs[win][(row0 + lr) * 40 + lg * 8];
        f32x4_t s[4];
        f32x4_t zero = {};
#pragma unroll
        for (int j = 0; j < 4; ++j) {
            bf16x8_t bk = *(const bf16x8_t*)&ks[win][(j * 16 + lr) * 40 + lg * 8];
            s[j] = MFMA16(aq, bk, zero);
        }

        // ---------------- softmax (wave-parallel over 16-lane groups) --------
        float mx[4] = {-1e30f, -1e30f, -1e30f, -1e30f};
#pragma unroll
        for (int j = 0; j < 4; ++j)
#pragma unroll
            for (int r = 0; r < 4; ++r) {
                float t = s[j][r] * SCALE + rm[j][r];
                s[j][r] = t;
                mx[r] = fmaxf(mx[r], t);
            }
#pragma unroll
        for (int r = 0; r < 4; ++r) {
            float m = mx[r];
            m = fmaxf(m, __shfl_xor(m, 1));
            m = fmaxf(m, __shfl_xor(m, 2));
            m = fmaxf(m, __shfl_xor(m, 4));
            m = fmaxf(m, __shfl_xor(m, 8));
            mx[r] = m;
        }
        float sm[4] = {0.f, 0.f, 0.f, 0.f};
#pragma unroll
        for (int j = 0; j < 4; ++j)
#pragma unroll
            for (int r = 0; r < 4; ++r) {
                float e = __expf(s[j][r] - mx[r]);
                s[j][r] = e;
                sm[r] += e;
            }
#pragma unroll
        for (int r = 0; r < 4; ++r) {
            float ssum = sm[r];
            ssum += __shfl_xor(ssum, 1);
            ssum += __shfl_xor(ssum, 2);
            ssum += __shfl_xor(ssum, 4);
            ssum += __shfl_xor(ssum, 8);
            sm[r] = 1.0f / ssum;       // normalize after PV
        }
        // write unnormalized P (own strip -> no extra barrier before PV)
#pragma unroll
        for (int j = 0; j < 4; ++j)
#pragma unroll
            for (int r = 0; r < 4; ++r)
                ps[win][(row0 + lg * 4 + r) * 72 + j * 16 + lr] = (bf16)s[j][r];

        // ---------------- O = P V (strip 16 x 32), K=64 ----------------------
        f32x4_t o[2] = {};
#pragma unroll
        for (int kh = 0; kh < 2; ++kh) {
            bf16x8_t pa = *(const bf16x8_t*)&ps[win][(row0 + lr) * 72 + kh * 32 + lg * 8];
#pragma unroll
            for (int jd = 0; jd < 2; ++jd) {
                bf16x8_t bv = *(const bf16x8_t*)&vts[win][(jd * 16 + lr) * 72 + kh * 32 + lg * 8];
                o[jd] = MFMA16(pa, bv, o[jd]);
            }
        }
#pragma unroll
        for (int jd = 0; jd < 2; ++jd)
#pragma unroll
            for (int r = 0; r < 4; ++r) {
                int row = row0 + lg * 4 + r;
                ao[((size_t)(b2 * 64 + row)) * 512 + h * 32 + jd * 16 + lr] =
                    (bf16)(o[jd][r] * sm[r]);
            }
        // next head's LDS writes are gated by its kt-loop barriers
    }
}

// ---------------------------------------------------------------------------
// Kernel 3: proj GEMM. C[131072,512] = A[131072,512]@B^T[512,512] + bias.
// 128x128 tile, BK=32, 4 waves. XCD-grouped block order: the 4 N-blocks of an
// M-panel run on the same XCD -> A panel L2 reuse.
// ---------------------------------------------------------------------------
__global__ __launch_bounds__(256) void k_proj(
    const bf16* __restrict__ A, const bf16* __restrict__ Bw,
    const float* __restrict__ bias, float* __restrict__ C)
{
    __shared__ bf16 As[128 * 40];
    __shared__ bf16 Bs[128 * 40];

    const int tid  = threadIdx.x;
    const int lane = tid & 63;
    const int wave = tid >> 6;
    const int lr = lane & 15, lg = lane >> 4;
    const int wr = wave >> 1, wc = wave & 1;
    // bijective XCD swizzle: bids with equal (bid&7) -> same XCD (round-robin),
    // handle contiguous wg chunk -> consecutive (same-mb) tiles share L2.
    const int bid = blockIdx.x;                  // 0..4095
    const int wg  = (bid & 7) * 512 + (bid >> 3);
    const int mb = wg >> 2, nb = wg & 3;
    const size_t m0 = (size_t)mb * 128;
    const int n0 = nb * 128;

    f32x4_t acc[4][4] = {};

    for (int kt = 0; kt < 16; ++kt) {
        const int k0 = kt * 32;
        bf16x8_t va[2], vb[2];
#pragma unroll
        for (int j = 0; j < 2; ++j) {
            int c = tid + 256 * j;
            int row = c >> 2, i8 = (c & 3) * 8;
            va[j] = *(const bf16x8_t*)(A  + (m0 + row) * 512 + k0 + i8);
            vb[j] = *(const bf16x8_t*)(Bw + (size_t)(n0 + row) * 512 + k0 + i8);
        }
        __syncthreads();
#pragma unroll
        for (int j = 0; j < 2; ++j) {
            int c = tid + 256 * j;
            int row = c >> 2, i8 = (c & 3) * 8;
            *(bf16x8_t*)&As[row * 40 + i8] = va[j];
            *(bf16x8_t*)&Bs[row * 40 + i8] = vb[j];
        }
        __syncthreads();

        bf16x8_t af[4], bfr[4];
#pragma unroll
        for (int i = 0; i < 4; ++i)
            af[i] = *(const bf16x8_t*)&As[(wr * 64 + i * 16 + lr) * 40 + lg * 8];
#pragma unroll
        for (int j = 0; j < 4; ++j)
            bfr[j] = *(const bf16x8_t*)&Bs[(wc * 64 + j * 16 + lr) * 40 + lg * 8];
#pragma unroll
        for (int i = 0; i < 4; ++i)
#pragma unroll
            for (int j = 0; j < 4; ++j)
                acc[i][j] = MFMA16(af[i], bfr[j], acc[i][j]);
    }

    float bj[4];
#pragma unroll
    for (int j = 0; j < 4; ++j) bj[j] = bias[n0 + wc * 64 + j * 16 + lr];
#pragma unroll
    for (int i = 0; i < 4; ++i) {
#pragma unroll
        for (int j = 0; j < 4; ++j) {
            int col = n0 + wc * 64 + j * 16 + lr;
#pragma unroll
            for (int r = 0; r < 4; ++r) {
                size_t row = m0 + wr * 64 + i * 16 + lg * 4 + r;
                C[row * 512 + col] = acc[i][j][r] + bj[j];
            }
        }
    }
}

// ---------------------------------------------------------------------------
extern "C" void kernel_launch(void* const* d_in, const int* in_sizes, int n_in,
                              void* d_out, int out_size, void* d_ws, size_t ws_size,
                              hipStream_t stream) {
    (void)in_sizes; (void)n_in; (void)out_size; (void)ws_size;
    const float* x      = (const float*)d_in[0];
    const float* pe     = (const float*)d_in[1];
    const float* rpe    = (const float*)d_in[2];
    const float* mask   = (const float*)d_in[3];
    const float* qkv_w  = (const float*)d_in[4];
    const float* qkv_b  = (const float*)d_in[5];
    const float* proj_w = (const float*)d_in[6];
    const float* proj_b = (const float*)d_in[7];
    float* out = (float*)d_out;

    char* ws = (char*)d_ws;
    bf16* wqkvb  = (bf16*)ws;                    // 1,572,864 B
    bf16* wprojb = (bf16*)(ws + 1572864);        //   524,288 B
    bf16* ao     = (bf16*)(ws + 2097152);        // 134,217,728 B

    k_wprep<<<256, 256, 0, stream>>>(qkv_w, proj_w, wqkvb, wprojb);
    k_qkv_attn<<<1024, 512, 0, stream>>>(x, pe, rpe, mask, qkv_b, wqkvb, ao);
    k_proj<<<4096, 256, 0, stream>>>(ao, wprojb, proj_b, out);
}

// Round 3
// 675.078 us; speedup vs baseline: 1.1289x; 1.1289x over previous
//
#include <hip/hip_runtime.h>
#include <hip/hip_bf16.h>
#include <cstdint>

// Problem constants: B_=2048 windows, N=64 tokens, C=512, H=16 heads, hd=32, nW=64.
typedef __bf16 bf16;
typedef __bf16 bf16x8_t __attribute__((ext_vector_type(8)));
typedef __bf16 bf16x4_t __attribute__((ext_vector_type(4)));
typedef float  f32x4_t  __attribute__((ext_vector_type(4)));

#define MFMA16(a, b, c) __builtin_amdgcn_mfma_f32_16x16x32_bf16((a), (b), (c), 0, 0, 0)

__device__ __forceinline__ void gload_lds16(const bf16* g, bf16* l) {
    __builtin_amdgcn_global_load_lds(
        (const __attribute__((address_space(1))) void*)g,
        (__attribute__((address_space(3))) void*)l,
        16, 0, 0);
}

// ---------------------------------------------------------------------------
// Kernel 1: convert weights to bf16 (qkv_w 1536x512, proj_w 512x512)
// ---------------------------------------------------------------------------
__global__ void k_wprep(const float* __restrict__ wq, const float* __restrict__ wp,
                        bf16* __restrict__ wqb, bf16* __restrict__ wpb) {
    int t = blockIdx.x * 256 + threadIdx.x;
    int stride = gridDim.x * 256;
    for (int i = t; i < 196608; i += stride) {
        float4 v = ((const float4*)wq)[i];
        bf16x4_t o; o[0]=(bf16)v.x; o[1]=(bf16)v.y; o[2]=(bf16)v.z; o[3]=(bf16)v.w;
        ((bf16x4_t*)wqb)[i] = o;
    }
    for (int i = t; i < 65536; i += stride) {
        float4 v = ((const float4*)wp)[i];
        bf16x4_t o; o[0]=(bf16)v.x; o[1]=(bf16)v.y; o[2]=(bf16)v.z; o[3]=(bf16)v.w;
        ((bf16x4_t*)wpb)[i] = o;
    }
}

// Stage one W head-tile phase (h, kt): 24 KB via 24 global_load_lds_dwordx4,
// 3 per wave. Source piece pre-swizzled, read applies same involution.
__device__ __forceinline__ void stage_ws(const bf16* __restrict__ wq, bf16* wsbuf,
                                         int h, int kt, int wave, int lane) {
#pragma unroll
    for (int ii = 0; ii < 3; ++ii) {
        int instr = wave * 3 + ii;            // 0..23, each covers 1 KB of LDS
        int rr = instr * 4 + (lane >> 4);     // LDS row 0..95
        int s  = lane & 15;                   // physical 16B piece in row
        int gp = (s & 8) | ((s & 7) ^ (rr & 7));          // logical piece
        int R  = ((rr >> 5) << 9) + (h << 5) + (rr & 31); // W global row
        gload_lds16(wq + (size_t)R * 512 + kt * 128 + gp * 8, wsbuf + instr * 512);
    }
}

// ---------------------------------------------------------------------------
// Kernel 2: fused QKV-projection + window attention.
// 1024 blocks x 512 threads (8 waves). Each block: 2 windows.
// Double-buffered Ws + raw barriers + counted vmcnt(3): staging loads for
// phase p+1 are in flight while phase p computes; no full vmcnt(0) drains
// in the K-loop. Attention barriers are lgkm-only so prefetch survives.
// ---------------------------------------------------------------------------
__global__ __launch_bounds__(512) void k_qkv_attn(
    const float* __restrict__ x,     // (2048,64,512) f32
    const float* __restrict__ pe,    // (64,512) f32
    const float* __restrict__ rpe,   // (16,64,64) f32
    const float* __restrict__ mask,  // (64,64,64) f32
    const float* __restrict__ qkv_b, // (1536,) f32
    const bf16*  __restrict__ wq,    // (1536,512) bf16
    bf16* __restrict__ ao)           // (2048,64,512) bf16 out
{
    __shared__ bf16 Ws[2][96 * 128];  // dbuf [96][128] XOR-swizzled, 2x24576 B
    __shared__ bf16 qs[2][64 * 40];   // q   [64][32] pad 40, per window
    __shared__ bf16 ks[2][64 * 40];   // k
    __shared__ bf16 vts[2][32 * 72];  // v^T [32][64] pad 72
    __shared__ bf16 ps[2][64 * 72];   // P   [64][64] pad 72
    // total LDS = 97,280 B -> 1 block/CU (8 waves)

    const int tid  = threadIdx.x;
    const int lane = tid & 63;
    const int wave = tid >> 6;
    const int win  = wave >> 2;       // 0/1: which window of the pair
    const int lr   = lane & 15;
    const int lg   = lane >> 4;
    const int row0 = (wave & 3) * 16;
    const int b2   = blockIdx.x * 2 + win;
    const int wi   = b2 & 63;         // mask window index

    // ---- xp strip into registers: a[kc] covers k = kc*32 + lg*8 .. +8
    bf16x8_t a[16];
    {
        const float* xr = x  + ((size_t)(b2 * 64 + row0 + lr)) * 512;
        const float* pr = pe + (size_t)(row0 + lr) * 512;
#pragma unroll
        for (int kc = 0; kc < 16; ++kc) {
            int k = kc * 32 + lg * 8;
            float4 x0 = *(const float4*)(xr + k);
            float4 x1 = *(const float4*)(xr + k + 4);
            float4 p0 = *(const float4*)(pr + k);
            float4 p1 = *(const float4*)(pr + k + 4);
            bf16x8_t v;
            v[0]=(bf16)(x0.x+p0.x); v[1]=(bf16)(x0.y+p0.y);
            v[2]=(bf16)(x0.z+p0.z); v[3]=(bf16)(x0.w+p0.w);
            v[4]=(bf16)(x1.x+p1.x); v[5]=(bf16)(x1.y+p1.y);
            v[6]=(bf16)(x1.z+p1.z); v[7]=(bf16)(x1.w+p1.w);
            a[kc] = v;
        }
    }

    const float SCALE = 0.17677669529663687f;  // 32^-0.5

    // prologue: stage phase 0 into buffer 0
    stage_ws(wq, Ws[0], 0, 0, wave, lane);

    for (int h = 0; h < 16; ++h) {
        // ---------------- QKV head-GEMM: out 64x96 (q|k|v) per window, K=512
        f32x4_t acc[6] = {};
#pragma unroll
        for (int kt = 0; kt < 4; ++kt) {          // BK=128; buffer = kt&1
            const int ph = h * 4 + kt;
            if (ph < 63) {
                const int pn = ph + 1;            // stage next phase -> other buf
                stage_ws(wq, Ws[(kt + 1) & 1], pn >> 2, pn & 3, wave, lane);
                asm volatile("s_waitcnt vmcnt(3)" ::: "memory");  // cur loads done
            } else {
                asm volatile("s_waitcnt vmcnt(0)" ::: "memory");
            }
            __builtin_amdgcn_s_barrier();         // buf[kt&1] visible to all
#pragma unroll
            for (int k2 = 0; k2 < 4; ++k2) {
                const int kc = kt * 4 + k2;       // compile-time
#pragma unroll
                for (int j = 0; j < 6; ++j) {
                    int row  = j * 16 + lr;
                    int p    = k2 * 4 + lg;
                    int phys = (p & 8) | ((p & 7) ^ (row & 7));
                    bf16x8_t bfrag = *(const bf16x8_t*)&Ws[kt & 1][row * 128 + phys * 8];
                    acc[j] = MFMA16(a[kc], bfrag, acc[j]);
                }
            }
            asm volatile("s_waitcnt lgkmcnt(0)" ::: "memory");  // reads retired
            __builtin_amdgcn_s_barrier();         // safe to overwrite this buf
        }

        // ---------------- bias + scatter q/k/v to LDS ------------------------
#pragma unroll
        for (int j = 0; j < 6; ++j) {
            int which = j >> 1;
            int colh  = (j & 1) * 16 + lr;
            float bj = qkv_b[which * 512 + h * 32 + colh];
#pragma unroll
            for (int r = 0; r < 4; ++r) {
                int row = row0 + lg * 4 + r;
                float val = acc[j][r] + bj;
                if (which == 0)      qs[win][row * 40 + colh] = (bf16)val;
                else if (which == 1) ks[win][row * 40 + colh] = (bf16)val;
                else                 vts[win][colh * 72 + row] = (bf16)val;
            }
        }
        asm volatile("s_waitcnt lgkmcnt(0)" ::: "memory");  // my writes landed
        __builtin_amdgcn_s_barrier();             // all waves' q/k/v visible

        // ---------------- prefetch rpe+mask (hides L2 latency under S-MFMA) --
        const float* rp = rpe  + ((size_t)h)  * 4096;
        const float* mp = mask + ((size_t)wi) * 4096;
        float rm[4][4];
#pragma unroll
        for (int j = 0; j < 4; ++j) {
            int col = j * 16 + lr;
#pragma unroll
            for (int r = 0; r < 4; ++r) {
                int row = row0 + lg * 4 + r;
                rm[j][r] = rp[row * 64 + col] + mp[row * 64 + col];
            }
        }

        // ---------------- S = q k^T (strip 16 x 64), K=32 --------------------
        bf16x8_t aq = *(const bf16x8_t*)&qs[win][(row0 + lr) * 40 + lg * 8];
        f32x4_t s[4];
        f32x4_t zero = {};
#pragma unroll
        for (int j = 0; j < 4; ++j) {
            bf16x8_t bk = *(const bf16x8_t*)&ks[win][(j * 16 + lr) * 40 + lg * 8];
            s[j] = MFMA16(aq, bk, zero);
        }

        // ---------------- softmax (wave-parallel over 16-lane groups) --------
        float mx[4] = {-1e30f, -1e30f, -1e30f, -1e30f};
#pragma unroll
        for (int j = 0; j < 4; ++j)
#pragma unroll
            for (int r = 0; r < 4; ++r) {
                float t = s[j][r] * SCALE + rm[j][r];
                s[j][r] = t;
                mx[r] = fmaxf(mx[r], t);
            }
#pragma unroll
        for (int r = 0; r < 4; ++r) {
            float m = mx[r];
            m = fmaxf(m, __shfl_xor(m, 1));
            m = fmaxf(m, __shfl_xor(m, 2));
            m = fmaxf(m, __shfl_xor(m, 4));
            m = fmaxf(m, __shfl_xor(m, 8));
            mx[r] = m;
        }
        float sm[4] = {0.f, 0.f, 0.f, 0.f};
#pragma unroll
        for (int j = 0; j < 4; ++j)
#pragma unroll
            for (int r = 0; r < 4; ++r) {
                float e = __expf(s[j][r] - mx[r]);
                s[j][r] = e;
                sm[r] += e;
            }
#pragma unroll
        for (int r = 0; r < 4; ++r) {
            float ssum = sm[r];
            ssum += __shfl_xor(ssum, 1);
            ssum += __shfl_xor(ssum, 2);
            ssum += __shfl_xor(ssum, 4);
            ssum += __shfl_xor(ssum, 8);
            sm[r] = 1.0f / ssum;       // normalize after PV
        }
        // write unnormalized P (own strip -> no extra barrier before PV)
#pragma unroll
        for (int j = 0; j < 4; ++j)
#pragma unroll
            for (int r = 0; r < 4; ++r)
                ps[win][(row0 + lg * 4 + r) * 72 + j * 16 + lr] = (bf16)s[j][r];

        // ---------------- O = P V (strip 16 x 32), K=64 ----------------------
        f32x4_t o[2] = {};
#pragma unroll
        for (int kh = 0; kh < 2; ++kh) {
            bf16x8_t pa = *(const bf16x8_t*)&ps[win][(row0 + lr) * 72 + kh * 32 + lg * 8];
#pragma unroll
            for (int jd = 0; jd < 2; ++jd) {
                bf16x8_t bv = *(const bf16x8_t*)&vts[win][(jd * 16 + lr) * 72 + kh * 32 + lg * 8];
                o[jd] = MFMA16(pa, bv, o[jd]);
            }
        }
#pragma unroll
        for (int jd = 0; jd < 2; ++jd)
#pragma unroll
            for (int r = 0; r < 4; ++r) {
                int row = row0 + lg * 4 + r;
                ao[((size_t)(b2 * 64 + row)) * 512 + h * 32 + jd * 16 + lr] =
                    (bf16)(o[jd][r] * sm[r]);
            }
        // next head's attention reads are gated by its own GEMM-phase barriers
    }
}

// ---------------------------------------------------------------------------
// Kernel 3: proj GEMM. C[131072,512] = A[131072,512]@B^T[512,512] + bias.
// 128x128 tile, BK=64 (8 iters), 4 waves, padded LDS (stride 72 -> b128 reads
// at the even 8-lane/slot floor). XCD-grouped block order for A-panel L2 reuse.
// ---------------------------------------------------------------------------
__global__ __launch_bounds__(256) void k_proj(
    const bf16* __restrict__ A, const bf16* __restrict__ Bw,
    const float* __restrict__ bias, float* __restrict__ C)
{
    __shared__ bf16 As[128 * 72];
    __shared__ bf16 Bs[128 * 72];

    const int tid  = threadIdx.x;
    const int lane = tid & 63;
    const int wave = tid >> 6;
    const int lr = lane & 15, lg = lane >> 4;
    const int wr = wave >> 1, wc = wave & 1;
    const int bid = blockIdx.x;                  // 0..4095
    const int wg  = (bid & 7) * 512 + (bid >> 3);
    const int mb = wg >> 2, nb = wg & 3;
    const size_t m0 = (size_t)mb * 128;
    const int n0 = nb * 128;

    f32x4_t acc[4][4] = {};

    for (int kt = 0; kt < 8; ++kt) {
        const int k0 = kt * 64;
        bf16x8_t va[4], vb[4];
#pragma unroll
        for (int j = 0; j < 4; ++j) {
            int c = tid + 256 * j;               // 1024 chunks: row=c>>3, i8=(c&7)*8
            int row = c >> 3, i8 = (c & 7) * 8;
            va[j] = *(const bf16x8_t*)(A  + (m0 + row) * 512 + k0 + i8);
            vb[j] = *(const bf16x8_t*)(Bw + (size_t)(n0 + row) * 512 + k0 + i8);
        }
        __syncthreads();
#pragma unroll
        for (int j = 0; j < 4; ++j) {
            int c = tid + 256 * j;
            int row = c >> 3, i8 = (c & 7) * 8;
            *(bf16x8_t*)&As[row * 72 + i8] = va[j];
            *(bf16x8_t*)&Bs[row * 72 + i8] = vb[j];
        }
        __syncthreads();

#pragma unroll
        for (int k2 = 0; k2 < 2; ++k2) {
            bf16x8_t af[4], bfr[4];
#pragma unroll
            for (int i = 0; i < 4; ++i)
                af[i] = *(const bf16x8_t*)&As[(wr * 64 + i * 16 + lr) * 72 + k2 * 32 + lg * 8];
#pragma unroll
            for (int j = 0; j < 4; ++j)
                bfr[j] = *(const bf16x8_t*)&Bs[(wc * 64 + j * 16 + lr) * 72 + k2 * 32 + lg * 8];
#pragma unroll
            for (int i = 0; i < 4; ++i)
#pragma unroll
                for (int j = 0; j < 4; ++j)
                    acc[i][j] = MFMA16(af[i], bfr[j], acc[i][j]);
        }
    }

    float bj[4];
#pragma unroll
    for (int j = 0; j < 4; ++j) bj[j] = bias[n0 + wc * 64 + j * 16 + lr];
#pragma unroll
    for (int i = 0; i < 4; ++i) {
#pragma unroll
        for (int j = 0; j < 4; ++j) {
            int col = n0 + wc * 64 + j * 16 + lr;
#pragma unroll
            for (int r = 0; r < 4; ++r) {
                size_t row = m0 + wr * 64 + i * 16 + lg * 4 + r;
                C[row * 512 + col] = acc[i][j][r] + bj[j];
            }
        }
    }
}

// ---------------------------------------------------------------------------
extern "C" void kernel_launch(void* const* d_in, const int* in_sizes, int n_in,
                              void* d_out, int out_size, void* d_ws, size_t ws_size,
                              hipStream_t stream) {
    (void)in_sizes; (void)n_in; (void)out_size; (void)ws_size;
    const float* x      = (const float*)d_in[0];
    const float* pe     = (const float*)d_in[1];
    const float* rpe    = (const float*)d_in[2];
    const float* mask   = (const float*)d_in[3];
    const float* qkv_w  = (const float*)d_in[4];
    const float* qkv_b  = (const float*)d_in[5];
    const float* proj_w = (const float*)d_in[6];
    const float* proj_b = (const float*)d_in[7];
    float* out = (float*)d_out;

    char* ws = (char*)d_ws;
    bf16* wqkvb  = (bf16*)ws;                    // 1,572,864 B
    bf16* wprojb = (bf16*)(ws + 1572864);        //   524,288 B
    bf16* ao     = (bf16*)(ws + 2097152);        // 134,217,728 B

    k_wprep<<<256, 256, 0, stream>>>(qkv_w, proj_w, wqkvb, wprojb);
    k_qkv_attn<<<1024, 512, 0, stream>>>(x, pe, rpe, mask, qkv_b, wqkvb, ao);
    k_proj<<<4096, 256, 0, stream>>>(ao, wprojb, proj_b, out);
}